// Round 1
// baseline (44.213 us; speedup 1.0000x reference)
//
#include <hip/hip_runtime.h>
#include <math.h>

constexpr int   NN  = 262144;     // nodes
constexpr int   NE  = 1048576;    // edges
constexpr float DTc = 0.1f;
constexpr float W1 = 1.0f, W2 = 0.5f, W3 = 2.0f, W4 = 0.5f;
constexpr float EPSc = 1e-6f;

struct V3 { float x, y, z; };
struct Q4 { float x, y, z, w; };

__device__ __forceinline__ V3 v3(float x, float y, float z) { V3 r{x, y, z}; return r; }
__device__ __forceinline__ V3 vadd(V3 a, V3 b) { return v3(a.x + b.x, a.y + b.y, a.z + b.z); }
__device__ __forceinline__ V3 vsub(V3 a, V3 b) { return v3(a.x - b.x, a.y - b.y, a.z - b.z); }
__device__ __forceinline__ V3 vscale(float s, V3 a) { return v3(s * a.x, s * a.y, s * a.z); }
__device__ __forceinline__ V3 vcross(V3 a, V3 b) {
    return v3(a.y * b.z - a.z * b.y, a.z * b.x - a.x * b.z, a.x * b.y - a.y * b.x);
}
__device__ __forceinline__ float vdot(V3 a, V3 b) { return a.x * b.x + a.y * b.y + a.z * b.z; }

__device__ __forceinline__ Q4 qmul(Q4 a, Q4 b) {
    Q4 r;
    r.w = a.w * b.w - (a.x * b.x + a.y * b.y + a.z * b.z);
    r.x = a.w * b.x + b.w * a.x + (a.y * b.z - a.z * b.y);
    r.y = a.w * b.y + b.w * a.y + (a.z * b.x - a.x * b.z);
    r.z = a.w * b.z + b.w * a.z + (a.x * b.y - a.y * b.x);
    return r;
}
__device__ __forceinline__ Q4 qconj(Q4 q) { Q4 r{-q.x, -q.y, -q.z, q.w}; return r; }
__device__ __forceinline__ V3 qrot(Q4 q, V3 x) {
    V3 v = v3(q.x, q.y, q.z);
    V3 c1 = vadd(vcross(v, x), vscale(q.w, x));
    return vadd(x, vscale(2.0f, vcross(v, c1)));
}
__device__ __forceinline__ V3 so3_log(Q4 q) {
    V3 v = v3(q.x, q.y, q.z);
    float n = sqrtf(vdot(v, v));
    float theta = 2.0f * atan2f(n, q.w);
    float factor;
    if (n < EPSc) {
        float w_safe = (fabsf(q.w) < EPSc) ? 1.0f : q.w;
        factor = 2.0f / w_safe;
    } else {
        factor = theta / n;
    }
    return vscale(factor, v);
}

__global__ __launch_bounds__(256) void vigraph_kernel(
    const float* __restrict__ pose, const float* __restrict__ vel,
    const float* __restrict__ vmot, const float* __restrict__ imu_drot,
    const float* __restrict__ body_dvel, const float* __restrict__ body_dpos,
    const int* __restrict__ vlink, float* __restrict__ out)
{
    int tid = blockIdx.x * blockDim.x + threadIdx.x;
    if (tid < NE) {
        // ---- edge residual: pgerr = se3_log(inv(vmot) * inv(pose1) * pose2)
        int e = tid;
        const float* pm = vmot + 7 * (size_t)e;
        V3 tm = v3(pm[0], pm[1], pm[2]);
        Q4 qm = {pm[3], pm[4], pm[5], pm[6]};
        int i1 = vlink[2 * (size_t)e];
        int i2 = vlink[2 * (size_t)e + 1];
        const float* p1 = pose + 7 * (size_t)i1;
        const float* p2 = pose + 7 * (size_t)i2;
        V3 t1 = v3(p1[0], p1[1], p1[2]); Q4 q1 = {p1[3], p1[4], p1[5], p1[6]};
        V3 t2 = v3(p2[0], p2[1], p2[2]); Q4 q2 = {p2[3], p2[4], p2[5], p2[6]};

        // A = se3_inv(pose1)
        Q4 qa = qconj(q1);
        V3 ta = vscale(-1.0f, qrot(qa, t1));
        // B = A * pose2
        V3 tb = vadd(ta, qrot(qa, t2));
        Q4 qb = qmul(qa, q2);
        // C = se3_inv(vmot)
        Q4 qc = qconj(qm);
        V3 tc = vscale(-1.0f, qrot(qc, tm));
        // err = C * B
        V3 te = vadd(tc, qrot(qc, tb));
        Q4 qe = qmul(qc, qb);

        // se3_log(err)
        V3 phi = so3_log(qe);
        float th = sqrtf(vdot(phi, phi));
        float coef;
        if (th < EPSc) {
            coef = 1.0f / 12.0f + th * th / 720.0f;
        } else {
            float s, c;
            sincosf(th, &s, &c);
            coef = 1.0f / (th * th) - (1.0f + c) / (2.0f * th * s);
        }
        V3 pxt = vcross(phi, te);
        V3 tau = vadd(vsub(te, vscale(0.5f, pxt)), vscale(coef, vcross(phi, pxt)));

        float* o = out + 6 * (size_t)e;
        o[0] = W1 * tau.x; o[1] = W1 * tau.y; o[2] = W1 * tau.z;
        o[3] = W1 * phi.x; o[4] = W1 * phi.y; o[5] = W1 * phi.z;
    } else {
        // ---- node residuals (i in [0, NN-1))
        int i = tid - NE;
        if (i >= NN - 1) return;
        const float* pa = pose + 7 * (size_t)i;
        const float* pb = pose + 7 * (size_t)(i + 1);
        V3 tr1 = v3(pa[0], pa[1], pa[2]); Q4 r1 = {pa[3], pa[4], pa[5], pa[6]};
        V3 tr2 = v3(pb[0], pb[1], pb[2]); Q4 r2 = {pb[3], pb[4], pb[5], pb[6]};
        V3 v1 = v3(vel[3 * (size_t)i],       vel[3 * (size_t)i + 1],       vel[3 * (size_t)i + 2]);
        V3 v2 = v3(vel[3 * (size_t)(i + 1)], vel[3 * (size_t)(i + 1) + 1], vel[3 * (size_t)(i + 1) + 2]);
        V3 bdv = v3(body_dvel[3 * (size_t)i], body_dvel[3 * (size_t)i + 1], body_dvel[3 * (size_t)i + 2]);
        V3 bdp = v3(body_dpos[3 * (size_t)i], body_dpos[3 * (size_t)i + 1], body_dpos[3 * (size_t)i + 2]);
        Q4 idr = {imu_drot[4 * (size_t)i], imu_drot[4 * (size_t)i + 1],
                  imu_drot[4 * (size_t)i + 2], imu_drot[4 * (size_t)i + 3]};

        // adjvelerr = qrot(r1, body_dvel) - (vel[i+1]-vel[i])
        V3 imu_dvel = qrot(r1, bdv);
        V3 adjvel = vsub(imu_dvel, vsub(v2, v1));
        // imuroterr = so3_log(imu_drot * (conj(r1) * r2))
        Q4 qrel = qmul(idr, qmul(qconj(r1), r2));
        V3 imurot = so3_log(qrel);
        // transvelerr = (qrot(r1, body_dpos) + vel[i]*DT) - (trans[i+1]-trans[i])
        V3 imu_dpos = vadd(qrot(r1, bdp), vscale(DTc, v1));
        V3 transvel = vsub(imu_dpos, vsub(tr2, tr1));

        size_t base = (size_t)6 * NE;
        size_t nm1 = (size_t)(NN - 1);
        float* oa = out + base + 3 * (size_t)i;
        oa[0] = W2 * adjvel.x; oa[1] = W2 * adjvel.y; oa[2] = W2 * adjvel.z;
        float* ob = out + base + 3 * nm1 + 3 * (size_t)i;
        ob[0] = W3 * imurot.x; ob[1] = W3 * imurot.y; ob[2] = W3 * imurot.z;
        float* oc = out + base + 6 * nm1 + 3 * (size_t)i;
        oc[0] = W4 * transvel.x; oc[1] = W4 * transvel.y; oc[2] = W4 * transvel.z;
    }
}

extern "C" void kernel_launch(void* const* d_in, const int* in_sizes, int n_in,
                              void* d_out, int out_size, void* d_ws, size_t ws_size,
                              hipStream_t stream) {
    const float* pose      = (const float*)d_in[0];
    const float* vel       = (const float*)d_in[1];
    const float* vmot      = (const float*)d_in[2];
    const float* imu_drot  = (const float*)d_in[3];
    const float* body_dvel = (const float*)d_in[4];
    const float* body_dpos = (const float*)d_in[5];
    const int*   vlink     = (const int*)d_in[6];
    float* out = (float*)d_out;

    int total = NE + (NN - 1);
    int block = 256;
    int grid = (total + block - 1) / block;
    vigraph_kernel<<<grid, block, 0, stream>>>(pose, vel, vmot, imu_drot,
                                               body_dvel, body_dpos, vlink, out);
}